// Round 1
// baseline (271.382 us; speedup 1.0000x reference)
//
#include <hip/hip_runtime.h>
#include <math.h>

#define HEADS 8
#define D_IN 128
#define D_HEAD 16
#define D_OUT 128  // HEADS * D_HEAD

typedef unsigned short ushort_t;
typedef unsigned int uint_t;
typedef __attribute__((ext_vector_type(8))) short short8;
typedef __attribute__((ext_vector_type(4))) float floatx4;

// ---------------- helpers ----------------
static __device__ inline uint_t f32_to_bf16(float f) {
    uint_t u = __float_as_uint(f);
    return (u + 0x7fffu + ((u >> 16) & 1u)) >> 16;  // RTNE
}
static __device__ inline uint_t pack_bf16(float lo, float hi) {
    return (f32_to_bf16(hi) << 16) | f32_to_bf16(lo);
}
// HW packed cvt (RTNE, same bits as pack_bf16) — 1 VALU op instead of ~8
static __device__ inline uint_t cvtpk_bf16(float lo, float hi) {
    uint_t r;
    asm("v_cvt_pk_bf16_f32 %0, %1, %2" : "=v"(r) : "v"(lo), "v"(hi));
    return r;
}
static __device__ inline float bf_lo(uint_t p) { return __uint_as_float(p << 16); }
static __device__ inline float bf_hi(uint_t p) { return __uint_as_float(p & 0xffff0000u); }

// ---------------- kernel 0: prep (unchanged) ----------------
#define PREP_WBLOCKS 64
__global__ __launch_bounds__(256) void prep_kernel(
    const float* __restrict__ Wg,
    const float* __restrict__ a1, const float* __restrict__ a2,
    ushort_t* __restrict__ Wfrag,
    const int* __restrict__ src, int* __restrict__ row_ptr, int n, int e)
{
    const int rp_blocks = (e + 1 + 255) / 256;
    const int bid = blockIdx.x;
    if (bid < PREP_WBLOCKS) {
        int t = bid * 256 + threadIdx.x;   // 0..16383
        int j    = t & 7;
        int lane = (t >> 3) & 63;
        int ks   = (t >> 9) & 3;
        int ct   = t >> 11;
        int k = ks * 32 + (lane >> 4) * 8 + j;
        int m = lane & 15;
        float v = Wg[(size_t)ct * (D_IN * D_HEAD) + k * D_HEAD + m];
        Wfrag[t] = (ushort_t)f32_to_bf16(v);
    } else if (bid < PREP_WBLOCKS + rp_blocks) {
        int i = (bid - PREP_WBLOCKS) * 256 + threadIdx.x;  // 0..e
        if (i > e) return;
        int sp = (i == 0) ? -1 : src[i - 1];
        int sc = (i == e) ? n  : src[i];
        for (int node = sp + 1; node <= sc; ++node) row_ptr[node] = i;
    } else {
#pragma unroll
        for (int i = 0; i < 8; ++i) {
            int t = i * 256 + threadIdx.x;       // 0..2047
            int j  = t & 7;
            int ln = (t >> 3) & 63;
            int ks = (t >> 9) & 3;
            int k  = ks * 32 + (ln >> 4) * 8 + j;
            int mm = ln & 15;
            int h  = mm & 7;
            const float* wrow = Wg + (size_t)h * (D_IN * D_HEAD) + k * D_HEAD;
            const float* av   = (mm < 8 ? a1 : a2) + h * D_HEAD;
            float s = 0.f;
#pragma unroll
            for (int o = 0; o < D_HEAD; ++o) s = fmaf(wrow[o], av[o], s);
            Wfrag[8 * 2048 + t] = (ushort_t)f32_to_bf16(s);
        }
    }
}

// ---------------- kernel 1: MFMA GEMM — no LDS, no barriers ----------------
// B-fragment loaded straight from global x (lane owns 8 consecutive channels of
// one node) and packed in-register; W fragments (36 KB, broadcast) read from
// global and served by L1/L2. Pure streaming: occupancy no longer LDS-capped,
// no stage->barrier->compute drain.
__global__ __launch_bounds__(256) void gemm_feats_mfma(
    const float* __restrict__ x, const ushort_t* __restrict__ Wfrag,
    const float* __restrict__ b1, const float* __restrict__ b2,
    ushort_t* __restrict__ feats, float* __restrict__ f1,
    float* __restrict__ f2, int n)
{
    const int tid  = threadIdx.x;
    const int wave = tid >> 6;
    const int lane = tid & 63;
    const int m    = lane & 15;
    const int kg   = lane >> 4;
    const int node = blockIdx.x * 64 + wave * 16 + m;
    const bool valid = node < n;

    floatx4 acc[9];
#pragma unroll
    for (int ct = 0; ct < 9; ++ct) acc[ct] = (floatx4){0.f, 0.f, 0.f, 0.f};

    const float* xp = x + (size_t)(valid ? node : 0) * D_IN + kg * 8;

#pragma unroll
    for (int ks = 0; ks < 4; ++ks) {
        float4 va = make_float4(0.f, 0.f, 0.f, 0.f), vb = va;
        if (valid) {
            va = *(const float4*)(xp + ks * 32);
            vb = *(const float4*)(xp + ks * 32 + 4);
        }
        union { uint_t u[4]; short8 s8; } cv;
        cv.u[0] = cvtpk_bf16(va.x, va.y);
        cv.u[1] = cvtpk_bf16(va.z, va.w);
        cv.u[2] = cvtpk_bf16(vb.x, vb.y);
        cv.u[3] = cvtpk_bf16(vb.z, vb.w);
        const short8 xb = cv.s8;
#pragma unroll
        for (int ct = 0; ct < 9; ++ct) {
            short8 wa = *(const short8*)(Wfrag + ((size_t)(ct * 4 + ks) * 64 + lane) * 8);
            acc[ct] = __builtin_amdgcn_mfma_f32_16x16x32_bf16(wa, xb, acc[ct], 0, 0, 0);
        }
    }

    if (valid) {
#pragma unroll
        for (int ct = 0; ct < 8; ++ct) {
            uint_t lo = cvtpk_bf16(acc[ct][0], acc[ct][1]);
            uint_t hi = cvtpk_bf16(acc[ct][2], acc[ct][3]);
            *(uint2*)(feats + (size_t)node * D_OUT + ct * 16 + kg * 4) = make_uint2(lo, hi);
        }
        const float* bb = (kg < 2) ? b1 : b2;
        float4 bv = *(const float4*)(bb + (kg & 1) * 4);
        float4 o = make_float4(acc[8][0] + bv.x, acc[8][1] + bv.y,
                               acc[8][2] + bv.z, acc[8][3] + bv.w);
        float* dstp = ((kg < 2) ? f1 : f2) + (size_t)node * HEADS + (kg & 1) * 4;
        *(float4*)dstp = o;
    }
}

// ---------------- kernel 2: per-node aggregation v2 ----------------
// One wave per node. 16-edge chunks with CLAMPED indices (no serial remainder
// tail — masked edges get w=0). Paired 8B gathers: lanes 0-31 read edge 2p's
// full 256B feats row (4 ch/lane), lanes 32-63 read edge 2p+1's row → half the
// gather instructions & shfls of the 4B scheme. Parity halves folded at the
// end with shfl_xor(32).
__global__ __launch_bounds__(256) void aggregate_kernel(
    const int* __restrict__ row_ptr, const int* __restrict__ dst,
    const ushort_t* __restrict__ feats,
    const float* __restrict__ f1, const float* __restrict__ f2,
    float* __restrict__ out, int n)
{
    int node = blockIdx.x * 4 + (threadIdx.x >> 6);
    node = __builtin_amdgcn_readfirstlane(node);   // wave-uniform -> scalar loads
    if (node >= n) return;
    const int lane = threadIdx.x & 63;
    // producer role: lane (h = lane>>3, q = lane&7) computes w for edges e+q (bank A)
    // and e+8+q (bank B) of head h.
    const int h  = lane >> 3;
    const int q  = lane & 7;
    // consumer role: parity hf = lane>>5 handles edges 2p+hf; sl = lane&31 owns
    // channels 4sl..4sl+3 (head sl>>2).
    const int hf    = lane >> 5;
    const int sl    = lane & 31;
    const int sbase = (sl >> 2) * 8 + hf;          // bpermute source base

    const float f1v  = f1[(size_t)node * HEADS + h];
    const int  start = row_ptr[node];
    const int  end   = row_ptr[node + 1];

    float s = 0.f, c0 = 0.f, c1 = 0.f, c2 = 0.f, c3 = 0.f;

    for (int e = start; e < end; e += 16) {
        // 16 clamped edge indices — uniform addresses -> SGPR loads
        int d[16];
#pragma unroll
        for (int t = 0; t < 16; ++t) {
            int ee = e + t;
            d[t] = dst[ee < end ? ee : end - 1];
        }
        // two weights per lane (edges e+q and e+8+q, head h)
        const int ea = e + q, eb = e + 8 + q;
        const int da = dst[ea < end ? ea : end - 1];   // vector 4B loads
        const int db = dst[eb < end ? eb : end - 1];
        float za = f1v + f2[(size_t)da * HEADS + h];
        float zb = f1v + f2[(size_t)db * HEADS + h];
        za = fmaxf(za, 0.2f * za);                     // leaky_relu
        zb = fmaxf(zb, 0.2f * zb);
        const float wa = (ea < end) ? __expf(za) : 0.f;
        const float wb = (eb < end) ? __expf(zb) : 0.f;

#pragma unroll
        for (int p = 0; p < 8; ++p) {
            const int row = hf ? d[2 * p + 1] : d[2 * p];
            const uint2 pr = *(const uint2*)(feats + (size_t)row * D_OUT + 4 * sl);
            const float w = __shfl(p < 4 ? wa : wb, sbase + ((2 * p) & 7));
            s  += w;
            c0 = fmaf(w, bf_lo(pr.x), c0);
            c1 = fmaf(w, bf_hi(pr.x), c1);
            c2 = fmaf(w, bf_lo(pr.y), c2);
            c3 = fmaf(w, bf_hi(pr.y), c3);
        }
    }

    // fold the two edge-parity halves (lane l <-> l^32 own the same channels)
    s  += __shfl_xor(s, 32);
    c0 += __shfl_xor(c0, 32);
    c1 += __shfl_xor(c1, 32);
    c2 += __shfl_xor(c2, 32);
    c3 += __shfl_xor(c3, 32);

    if (lane < 32) {
        float4 r = make_float4(0.f, 0.f, 0.f, 0.f);
        if (end > start) {
            const float inv = 1.f / s;
            r.x = c0 * inv; r.y = c1 * inv; r.z = c2 * inv; r.w = c3 * inv;
            r.x = r.x > 0.f ? r.x : expm1f(r.x);       // elu
            r.y = r.y > 0.f ? r.y : expm1f(r.y);
            r.z = r.z > 0.f ? r.z : expm1f(r.z);
            r.w = r.w > 0.f ? r.w : expm1f(r.w);
        }
        *(float4*)(out + (size_t)node * D_OUT + 4 * sl) = r;
    }
}

// ---------------- launch ----------------
extern "C" void kernel_launch(void* const* d_in, const int* in_sizes, int n_in,
                              void* d_out, int out_size, void* d_ws, size_t ws_size,
                              hipStream_t stream)
{
    const float* x  = (const float*)d_in[0];
    const float* W  = (const float*)d_in[1];
    const float* a1 = (const float*)d_in[2];
    const float* b1 = (const float*)d_in[3];
    const float* a2 = (const float*)d_in[4];
    const float* b2 = (const float*)d_in[5];
    const int* src  = (const int*)d_in[6];
    const int* dst  = (const int*)d_in[7];
    float* out = (float*)d_out;

    const int n = in_sizes[0] / D_IN;   // 100000
    const int e = in_sizes[6];          // 1600000

    // workspace carve-up
    char* ws = (char*)d_ws;
    size_t off = 0;
    ushort_t* feats = (ushort_t*)(ws + off);                // [n][128] bf16
    off += (size_t)n * D_OUT * sizeof(ushort_t); off = (off + 255) & ~(size_t)255;
    float* f1 = (float*)(ws + off);                         // [n][8]
    off += (size_t)n * HEADS * sizeof(float);    off = (off + 255) & ~(size_t)255;
    float* f2 = (float*)(ws + off);                         // [n][8]
    off += (size_t)n * HEADS * sizeof(float);    off = (off + 255) & ~(size_t)255;
    int* row_ptr = (int*)(ws + off);
    off += (size_t)(n + 1) * sizeof(int);        off = (off + 255) & ~(size_t)255;
    ushort_t* Wfrag = (ushort_t*)(ws + off);                // 9*2048 bf16

    dim3 blk(256);
    const int rp_blocks = (e + 1 + 255) / 256;
    prep_kernel<<<dim3(PREP_WBLOCKS + rp_blocks + 1), blk, 0, stream>>>(
        W, a1, a2, Wfrag, src, row_ptr, n, e);
    gemm_feats_mfma<<<dim3((n + 63) / 64), blk, 0, stream>>>(
        x, Wfrag, b1, b2, feats, f1, f2, n);
    aggregate_kernel<<<dim3((n + 3) / 4), blk, 0, stream>>>(
        row_ptr, dst, feats, f1, f2, out, n);
}

// Round 2
// 212.310 us; speedup vs baseline: 1.2782x; 1.2782x over previous
//
#include <hip/hip_runtime.h>
#include <math.h>

#define HEADS 8
#define D_IN 128
#define D_HEAD 16
#define D_OUT 128  // HEADS * D_HEAD

typedef unsigned short ushort_t;
typedef unsigned int uint_t;
typedef __attribute__((ext_vector_type(8))) short short8;
typedef __attribute__((ext_vector_type(4))) float floatx4;

// ---------------- helpers ----------------
static __device__ inline uint_t f32_to_bf16(float f) {
    uint_t u = __float_as_uint(f);
    return (u + 0x7fffu + ((u >> 16) & 1u)) >> 16;  // RTNE
}
static __device__ inline uint_t pack_bf16(float lo, float hi) {
    return (f32_to_bf16(hi) << 16) | f32_to_bf16(lo);
}
// HW packed cvt (RTNE, same bits as pack_bf16) — 1 VALU op instead of ~8
static __device__ inline uint_t cvtpk_bf16(float lo, float hi) {
    uint_t r;
    asm("v_cvt_pk_bf16_f32 %0, %1, %2" : "=v"(r) : "v"(lo), "v"(hi));
    return r;
}
static __device__ inline float bf_lo(uint_t p) { return __uint_as_float(p << 16); }
static __device__ inline float bf_hi(uint_t p) { return __uint_as_float(p & 0xffff0000u); }

// ---------------- kernel 0: prep (unchanged) ----------------
#define PREP_WBLOCKS 64
__global__ __launch_bounds__(256) void prep_kernel(
    const float* __restrict__ Wg,
    const float* __restrict__ a1, const float* __restrict__ a2,
    ushort_t* __restrict__ Wfrag,
    const int* __restrict__ src, int* __restrict__ row_ptr, int n, int e)
{
    const int rp_blocks = (e + 1 + 255) / 256;
    const int bid = blockIdx.x;
    if (bid < PREP_WBLOCKS) {
        int t = bid * 256 + threadIdx.x;   // 0..16383
        int j    = t & 7;
        int lane = (t >> 3) & 63;
        int ks   = (t >> 9) & 3;
        int ct   = t >> 11;
        int k = ks * 32 + (lane >> 4) * 8 + j;
        int m = lane & 15;
        float v = Wg[(size_t)ct * (D_IN * D_HEAD) + k * D_HEAD + m];
        Wfrag[t] = (ushort_t)f32_to_bf16(v);
    } else if (bid < PREP_WBLOCKS + rp_blocks) {
        int i = (bid - PREP_WBLOCKS) * 256 + threadIdx.x;  // 0..e
        if (i > e) return;
        int sp = (i == 0) ? -1 : src[i - 1];
        int sc = (i == e) ? n  : src[i];
        for (int node = sp + 1; node <= sc; ++node) row_ptr[node] = i;
    } else {
#pragma unroll
        for (int i = 0; i < 8; ++i) {
            int t = i * 256 + threadIdx.x;       // 0..2047
            int j  = t & 7;
            int ln = (t >> 3) & 63;
            int ks = (t >> 9) & 3;
            int k  = ks * 32 + (ln >> 4) * 8 + j;
            int mm = ln & 15;
            int h  = mm & 7;
            const float* wrow = Wg + (size_t)h * (D_IN * D_HEAD) + k * D_HEAD;
            const float* av   = (mm < 8 ? a1 : a2) + h * D_HEAD;
            float s = 0.f;
#pragma unroll
            for (int o = 0; o < D_HEAD; ++o) s = fmaf(wrow[o], av[o], s);
            Wfrag[8 * 2048 + t] = (ushort_t)f32_to_bf16(s);
        }
    }
}

// ---------------- kernel 1: MFMA GEMM — no LDS, no barriers (kept from R1) ---
__global__ __launch_bounds__(256) void gemm_feats_mfma(
    const float* __restrict__ x, const ushort_t* __restrict__ Wfrag,
    const float* __restrict__ b1, const float* __restrict__ b2,
    ushort_t* __restrict__ feats, float* __restrict__ f1,
    float* __restrict__ f2, int n)
{
    const int tid  = threadIdx.x;
    const int wave = tid >> 6;
    const int lane = tid & 63;
    const int m    = lane & 15;
    const int kg   = lane >> 4;
    const int node = blockIdx.x * 64 + wave * 16 + m;
    const bool valid = node < n;

    floatx4 acc[9];
#pragma unroll
    for (int ct = 0; ct < 9; ++ct) acc[ct] = (floatx4){0.f, 0.f, 0.f, 0.f};

    const float* xp = x + (size_t)(valid ? node : 0) * D_IN + kg * 8;

#pragma unroll
    for (int ks = 0; ks < 4; ++ks) {
        float4 va = make_float4(0.f, 0.f, 0.f, 0.f), vb = va;
        if (valid) {
            va = *(const float4*)(xp + ks * 32);
            vb = *(const float4*)(xp + ks * 32 + 4);
        }
        union { uint_t u[4]; short8 s8; } cv;
        cv.u[0] = cvtpk_bf16(va.x, va.y);
        cv.u[1] = cvtpk_bf16(va.z, va.w);
        cv.u[2] = cvtpk_bf16(vb.x, vb.y);
        cv.u[3] = cvtpk_bf16(vb.z, vb.w);
        const short8 xb = cv.s8;
#pragma unroll
        for (int ct = 0; ct < 9; ++ct) {
            short8 wa = *(const short8*)(Wfrag + ((size_t)(ct * 4 + ks) * 64 + lane) * 8);
            acc[ct] = __builtin_amdgcn_mfma_f32_16x16x32_bf16(wa, xb, acc[ct], 0, 0, 0);
        }
    }

    if (valid) {
#pragma unroll
        for (int ct = 0; ct < 8; ++ct) {
            uint_t lo = cvtpk_bf16(acc[ct][0], acc[ct][1]);
            uint_t hi = cvtpk_bf16(acc[ct][2], acc[ct][3]);
            *(uint2*)(feats + (size_t)node * D_OUT + ct * 16 + kg * 4) = make_uint2(lo, hi);
        }
        const float* bb = (kg < 2) ? b1 : b2;
        float4 bv = *(const float4*)(bb + (kg & 1) * 4);
        float4 o = make_float4(acc[8][0] + bv.x, acc[8][1] + bv.y,
                               acc[8][2] + bv.z, acc[8][3] + bv.w);
        float* dstp = ((kg < 2) ? f1 : f2) + (size_t)node * HEADS + (kg & 1) * 4;
        *(float4*)dstp = o;
    }
}

// ---------------- kernel 2: per-node aggregation v3 ----------------
// Round-0 structure (proven: 0 LDS, 0 bank conflicts, coalesced 256B row
// gathers) + masked tail: 16-edge chunks, indices CLAMPED to end-1, OOB edges
// get w=0. No serial remainder. Row indices forced into SGPRs with
// readfirstlane (wave-uniform addresses) -> blocks promote-alloca-to-LDS,
// zero VGPR cost, 16 gathers in flight.
__global__ __launch_bounds__(256) void aggregate_kernel(
    const int* __restrict__ row_ptr, const int* __restrict__ dst,
    const ushort_t* __restrict__ feats,
    const float* __restrict__ f1, const float* __restrict__ f2,
    float* __restrict__ out, int n)
{
    int node = blockIdx.x * 4 + (threadIdx.x >> 6);
    node = __builtin_amdgcn_readfirstlane(node);   // wave-uniform -> scalar loads
    if (node >= n) return;
    const int lane = threadIdx.x & 63;
    const int h = lane >> 3;                       // head for weight production
    const int q = lane & 7;                        // edge slot for weight production

    const float f1v   = f1[(size_t)node * HEADS + h];
    const int   start = row_ptr[node];
    const int   end   = row_ptr[node + 1];

    const ushort_t* fl = feats + 2 * lane;         // lane owns channels 2l, 2l+1

    float s = 0.f, ax = 0.f, ay = 0.f;

    for (int e = start; e < end; e += 16) {
        // 16 wave-uniform row indices in SGPRs (two 8-banks)
        int d0[8], d1[8];
#pragma unroll
        for (int t = 0; t < 8; ++t) {
            int ea = e + t;      ea = ea < end ? ea : end - 1;
            int eb = e + 8 + t;  eb = eb < end ? eb : end - 1;
            d0[t] = __builtin_amdgcn_readfirstlane(dst[ea]);
            d1[t] = __builtin_amdgcn_readfirstlane(dst[eb]);
        }
        // two weights per lane: edges e+q (wa) and e+8+q (wb), head h
        const int ea = e + q, eb = e + 8 + q;
        const int da = dst[ea < end ? ea : end - 1];
        const int db = dst[eb < end ? eb : end - 1];
        float za = f1v + f2[(size_t)da * HEADS + h];
        float zb = f1v + f2[(size_t)db * HEADS + h];
        za = fmaxf(za, 0.2f * za);                 // leaky_relu
        zb = fmaxf(zb, 0.2f * zb);
        const float wa = (ea < end) ? __expf(za) : 0.f;
        const float wb = (eb < end) ? __expf(zb) : 0.f;

        // 16 coalesced row gathers (one 256B feats row per load, saddr form)
        uint_t p0[8], p1[8];
#pragma unroll
        for (int t = 0; t < 8; ++t) {
            p0[t] = *(const uint_t*)(fl + (size_t)d0[t] * D_OUT);
            p1[t] = *(const uint_t*)(fl + (size_t)d1[t] * D_OUT);
        }
#pragma unroll
        for (int t = 0; t < 8; ++t) {
            const float w0 = __shfl(wa, (lane & 56) | t);
            s += w0;
            ax = fmaf(w0, bf_lo(p0[t]), ax);
            ay = fmaf(w0, bf_hi(p0[t]), ay);
        }
#pragma unroll
        for (int t = 0; t < 8; ++t) {
            const float w1 = __shfl(wb, (lane & 56) | t);
            s += w1;
            ax = fmaf(w1, bf_lo(p1[t]), ax);
            ay = fmaf(w1, bf_hi(p1[t]), ay);
        }
    }

    float rx = 0.f, ry = 0.f;
    if (end > start) {
        rx = ax / s;
        ry = ay / s;
        rx = rx > 0.f ? rx : expm1f(rx);   // elu
        ry = ry > 0.f ? ry : expm1f(ry);
    }
    *(float2*)(out + (size_t)node * D_OUT + 2 * lane) = make_float2(rx, ry);
}

// ---------------- launch ----------------
extern "C" void kernel_launch(void* const* d_in, const int* in_sizes, int n_in,
                              void* d_out, int out_size, void* d_ws, size_t ws_size,
                              hipStream_t stream)
{
    const float* x  = (const float*)d_in[0];
    const float* W  = (const float*)d_in[1];
    const float* a1 = (const float*)d_in[2];
    const float* b1 = (const float*)d_in[3];
    const float* a2 = (const float*)d_in[4];
    const float* b2 = (const float*)d_in[5];
    const int* src  = (const int*)d_in[6];
    const int* dst  = (const int*)d_in[7];
    float* out = (float*)d_out;

    const int n = in_sizes[0] / D_IN;   // 100000
    const int e = in_sizes[6];          // 1600000

    // workspace carve-up
    char* ws = (char*)d_ws;
    size_t off = 0;
    ushort_t* feats = (ushort_t*)(ws + off);                // [n][128] bf16
    off += (size_t)n * D_OUT * sizeof(ushort_t); off = (off + 255) & ~(size_t)255;
    float* f1 = (float*)(ws + off);                         // [n][8]
    off += (size_t)n * HEADS * sizeof(float);    off = (off + 255) & ~(size_t)255;
    float* f2 = (float*)(ws + off);                         // [n][8]
    off += (size_t)n * HEADS * sizeof(float);    off = (off + 255) & ~(size_t)255;
    int* row_ptr = (int*)(ws + off);
    off += (size_t)(n + 1) * sizeof(int);        off = (off + 255) & ~(size_t)255;
    ushort_t* Wfrag = (ushort_t*)(ws + off);                // 9*2048 bf16

    dim3 blk(256);
    const int rp_blocks = (e + 1 + 255) / 256;
    prep_kernel<<<dim3(PREP_WBLOCKS + rp_blocks + 1), blk, 0, stream>>>(
        W, a1, a2, Wfrag, src, row_ptr, n, e);
    gemm_feats_mfma<<<dim3((n + 63) / 64), blk, 0, stream>>>(
        x, Wfrag, b1, b2, feats, f1, f2, n);
    aggregate_kernel<<<dim3((n + 3) / 4), blk, 0, stream>>>(
        row_ptr, dst, feats, f1, f2, out, n);
}

// Round 3
// 211.216 us; speedup vs baseline: 1.2849x; 1.0052x over previous
//
#include <hip/hip_runtime.h>
#include <math.h>

#define HEADS 8
#define D_IN 128
#define D_HEAD 16
#define D_OUT 128  // HEADS * D_HEAD

typedef unsigned short ushort_t;
typedef unsigned int uint_t;
typedef __attribute__((ext_vector_type(8))) short short8;
typedef __attribute__((ext_vector_type(4))) float floatx4;

// ---------------- helpers ----------------
static __device__ inline uint_t f32_to_bf16(float f) {
    uint_t u = __float_as_uint(f);
    return (u + 0x7fffu + ((u >> 16) & 1u)) >> 16;  // RTNE
}
static __device__ inline uint_t pack_bf16(float lo, float hi) {
    return (f32_to_bf16(hi) << 16) | f32_to_bf16(lo);
}
// HW packed cvt (RTNE, same bits as pack_bf16) — 1 VALU op instead of ~8
static __device__ inline uint_t cvtpk_bf16(float lo, float hi) {
    uint_t r;
    asm("v_cvt_pk_bf16_f32 %0, %1, %2" : "=v"(r) : "v"(lo), "v"(hi));
    return r;
}
static __device__ inline float bf_lo(uint_t p) { return __uint_as_float(p << 16); }
static __device__ inline float bf_hi(uint_t p) { return __uint_as_float(p & 0xffff0000u); }

// ---------------- kernel 0: prep (unchanged) ----------------
#define PREP_WBLOCKS 64
__global__ __launch_bounds__(256) void prep_kernel(
    const float* __restrict__ Wg,
    const float* __restrict__ a1, const float* __restrict__ a2,
    ushort_t* __restrict__ Wfrag,
    const int* __restrict__ src, int* __restrict__ row_ptr, int n, int e)
{
    const int rp_blocks = (e + 1 + 255) / 256;
    const int bid = blockIdx.x;
    if (bid < PREP_WBLOCKS) {
        int t = bid * 256 + threadIdx.x;   // 0..16383
        int j    = t & 7;
        int lane = (t >> 3) & 63;
        int ks   = (t >> 9) & 3;
        int ct   = t >> 11;
        int k = ks * 32 + (lane >> 4) * 8 + j;
        int m = lane & 15;
        float v = Wg[(size_t)ct * (D_IN * D_HEAD) + k * D_HEAD + m];
        Wfrag[t] = (ushort_t)f32_to_bf16(v);
    } else if (bid < PREP_WBLOCKS + rp_blocks) {
        int i = (bid - PREP_WBLOCKS) * 256 + threadIdx.x;  // 0..e
        if (i > e) return;
        int sp = (i == 0) ? -1 : src[i - 1];
        int sc = (i == e) ? n  : src[i];
        for (int node = sp + 1; node <= sc; ++node) row_ptr[node] = i;
    } else {
#pragma unroll
        for (int i = 0; i < 8; ++i) {
            int t = i * 256 + threadIdx.x;       // 0..2047
            int j  = t & 7;
            int ln = (t >> 3) & 63;
            int ks = (t >> 9) & 3;
            int k  = ks * 32 + (ln >> 4) * 8 + j;
            int mm = ln & 15;
            int h  = mm & 7;
            const float* wrow = Wg + (size_t)h * (D_IN * D_HEAD) + k * D_HEAD;
            const float* av   = (mm < 8 ? a1 : a2) + h * D_HEAD;
            float s = 0.f;
#pragma unroll
            for (int o = 0; o < D_HEAD; ++o) s = fmaf(wrow[o], av[o], s);
            Wfrag[8 * 2048 + t] = (ushort_t)f32_to_bf16(s);
        }
    }
}

// ---------------- kernel 1: MFMA GEMM — no LDS, no barriers (kept from R1) ---
__global__ __launch_bounds__(256) void gemm_feats_mfma(
    const float* __restrict__ x, const ushort_t* __restrict__ Wfrag,
    const float* __restrict__ b1, const float* __restrict__ b2,
    ushort_t* __restrict__ feats, float* __restrict__ f1,
    float* __restrict__ f2, int n)
{
    const int tid  = threadIdx.x;
    const int wave = tid >> 6;
    const int lane = tid & 63;
    const int m    = lane & 15;
    const int kg   = lane >> 4;
    const int node = blockIdx.x * 64 + wave * 16 + m;
    const bool valid = node < n;

    floatx4 acc[9];
#pragma unroll
    for (int ct = 0; ct < 9; ++ct) acc[ct] = (floatx4){0.f, 0.f, 0.f, 0.f};

    const float* xp = x + (size_t)(valid ? node : 0) * D_IN + kg * 8;

#pragma unroll
    for (int ks = 0; ks < 4; ++ks) {
        float4 va = make_float4(0.f, 0.f, 0.f, 0.f), vb = va;
        if (valid) {
            va = *(const float4*)(xp + ks * 32);
            vb = *(const float4*)(xp + ks * 32 + 4);
        }
        union { uint_t u[4]; short8 s8; } cv;
        cv.u[0] = cvtpk_bf16(va.x, va.y);
        cv.u[1] = cvtpk_bf16(va.z, va.w);
        cv.u[2] = cvtpk_bf16(vb.x, vb.y);
        cv.u[3] = cvtpk_bf16(vb.z, vb.w);
        const short8 xb = cv.s8;
#pragma unroll
        for (int ct = 0; ct < 9; ++ct) {
            short8 wa = *(const short8*)(Wfrag + ((size_t)(ct * 4 + ks) * 64 + lane) * 8);
            acc[ct] = __builtin_amdgcn_mfma_f32_16x16x32_bf16(wa, xb, acc[ct], 0, 0, 0);
        }
    }

    if (valid) {
#pragma unroll
        for (int ct = 0; ct < 8; ++ct) {
            uint_t lo = cvtpk_bf16(acc[ct][0], acc[ct][1]);
            uint_t hi = cvtpk_bf16(acc[ct][2], acc[ct][3]);
            *(uint2*)(feats + (size_t)node * D_OUT + ct * 16 + kg * 4) = make_uint2(lo, hi);
        }
        const float* bb = (kg < 2) ? b1 : b2;
        float4 bv = *(const float4*)(bb + (kg & 1) * 4);
        float4 o = make_float4(acc[8][0] + bv.x, acc[8][1] + bv.y,
                               acc[8][2] + bv.z, acc[8][3] + bv.w);
        float* dstp = ((kg < 2) ? f1 : f2) + (size_t)node * HEADS + (kg & 1) * 4;
        *(float4*)dstp = o;
    }
}

// ---------------- kernel 2: per-node aggregation v4 — scalarized ----------------
// R2 structure + aggressive scalarization: start/end/edge indices/row indices
// all forced into SGPRs. Clamps become s_cselect, the 16 dst[] index loads
// become s_load on the scalar pipe, and each row gather is saddr-form
// (SGPR row base + lane voffset) -> ~zero VALU per gather. The remaining VALU
// is the irreducible MAC loop (shfl + unpack + 2 fma + add per edge-slot).
__global__ __launch_bounds__(256) void aggregate_kernel(
    const int* __restrict__ row_ptr, const int* __restrict__ dst,
    const ushort_t* __restrict__ feats,
    const float* __restrict__ f1, const float* __restrict__ f2,
    float* __restrict__ out, int n)
{
    int node = blockIdx.x * 4 + (threadIdx.x >> 6);
    node = __builtin_amdgcn_readfirstlane(node);   // wave-uniform -> scalar loads
    if (node >= n) return;
    const int lane = threadIdx.x & 63;
    const int h = lane >> 3;                       // head for weight production
    const int q = lane & 7;                        // edge slot for weight production

    // scalar loop bounds -> all downstream index math lands on the SALU
    const int start = __builtin_amdgcn_readfirstlane(row_ptr[node]);
    const int end   = __builtin_amdgcn_readfirstlane(row_ptr[node + 1]);

    const float f1v = f1[(size_t)node * HEADS + h];

    float s = 0.f, ax = 0.f, ay = 0.f;

    for (int e = start; e < end; e += 16) {
        // 16 scalar row indices (s_load via uniform clamped index)
        int d0[8], d1[8];
#pragma unroll
        for (int t = 0; t < 8; ++t) {
            int ea = e + t;      ea = ea < end ? ea : end - 1;       // SALU cselect
            int eb = e + 8 + t;  eb = eb < end ? eb : end - 1;
            d0[t] = __builtin_amdgcn_readfirstlane(dst[ea]);
            d1[t] = __builtin_amdgcn_readfirstlane(dst[eb]);
        }
        // two weights per lane: edges e+q (wa) and e+8+q (wb), head h
        const int ea = e + q, eb = e + 8 + q;
        const int da = dst[ea < end ? ea : end - 1];   // vector 32B loads
        const int db = dst[eb < end ? eb : end - 1];
        float za = f1v + f2[(size_t)da * HEADS + h];
        float zb = f1v + f2[(size_t)db * HEADS + h];
        za = fmaxf(za, 0.2f * za);                     // leaky_relu
        zb = fmaxf(zb, 0.2f * zb);
        const float wa = (ea < end) ? __expf(za) : 0.f;
        const float wb = (eb < end) ? __expf(zb) : 0.f;

        // 16 coalesced row gathers, saddr form: SGPR row base + lane voffset
        uint_t p0[8], p1[8];
#pragma unroll
        for (int t = 0; t < 8; ++t) {
            const ushort_t* r0 = feats + ((size_t)d0[t] << 7);   // scalar base
            const ushort_t* r1 = feats + ((size_t)d1[t] << 7);
            p0[t] = *(const uint_t*)(r0 + 2 * lane);
            p1[t] = *(const uint_t*)(r1 + 2 * lane);
        }
#pragma unroll
        for (int t = 0; t < 8; ++t) {
            const float w0 = __shfl(wa, (lane & 56) | t);
            s += w0;
            ax = fmaf(w0, bf_lo(p0[t]), ax);
            ay = fmaf(w0, bf_hi(p0[t]), ay);
        }
#pragma unroll
        for (int t = 0; t < 8; ++t) {
            const float w1 = __shfl(wb, (lane & 56) | t);
            s += w1;
            ax = fmaf(w1, bf_lo(p1[t]), ax);
            ay = fmaf(w1, bf_hi(p1[t]), ay);
        }
    }

    float rx = 0.f, ry = 0.f;
    if (end > start) {
        rx = ax / s;
        ry = ay / s;
        rx = rx > 0.f ? rx : expm1f(rx);   // elu
        ry = ry > 0.f ? ry : expm1f(ry);
    }
    *(float2*)(out + (size_t)node * D_OUT + 2 * lane) = make_float2(rx, ry);
}

// ---------------- launch ----------------
extern "C" void kernel_launch(void* const* d_in, const int* in_sizes, int n_in,
                              void* d_out, int out_size, void* d_ws, size_t ws_size,
                              hipStream_t stream)
{
    const float* x  = (const float*)d_in[0];
    const float* W  = (const float*)d_in[1];
    const float* a1 = (const float*)d_in[2];
    const float* b1 = (const float*)d_in[3];
    const float* a2 = (const float*)d_in[4];
    const float* b2 = (const float*)d_in[5];
    const int* src  = (const int*)d_in[6];
    const int* dst  = (const int*)d_in[7];
    float* out = (float*)d_out;

    const int n = in_sizes[0] / D_IN;   // 100000
    const int e = in_sizes[6];          // 1600000

    // workspace carve-up
    char* ws = (char*)d_ws;
    size_t off = 0;
    ushort_t* feats = (ushort_t*)(ws + off);                // [n][128] bf16
    off += (size_t)n * D_OUT * sizeof(ushort_t); off = (off + 255) & ~(size_t)255;
    float* f1 = (float*)(ws + off);                         // [n][8]
    off += (size_t)n * HEADS * sizeof(float);    off = (off + 255) & ~(size_t)255;
    float* f2 = (float*)(ws + off);                         // [n][8]
    off += (size_t)n * HEADS * sizeof(float);    off = (off + 255) & ~(size_t)255;
    int* row_ptr = (int*)(ws + off);
    off += (size_t)(n + 1) * sizeof(int);        off = (off + 255) & ~(size_t)255;
    ushort_t* Wfrag = (ushort_t*)(ws + off);                // 9*2048 bf16

    dim3 blk(256);
    const int rp_blocks = (e + 1 + 255) / 256;
    prep_kernel<<<dim3(PREP_WBLOCKS + rp_blocks + 1), blk, 0, stream>>>(
        W, a1, a2, Wfrag, src, row_ptr, n, e);
    gemm_feats_mfma<<<dim3((n + 63) / 64), blk, 0, stream>>>(
        x, Wfrag, b1, b2, feats, f1, f2, n);
    aggregate_kernel<<<dim3((n + 3) / 4), blk, 0, stream>>>(
        row_ptr, dst, feats, f1, f2, out, n);
}